// Round 1
// baseline (36.184 us; speedup 1.0000x reference)
//
#include <hip/hip_runtime.h>
#include <math.h>

#define N   512
#define DI  128
#define DO  128

// ---------------------------------------------------------------------------
// Kernel A: per-row projections.
//   f_src[j][d] = sum_k x[j][k] * Wf[d][k]
//   f_tgt[j][d] = sum_k x[j][k] * Wf[d][128+k]
//   s[j]        = sum_k x[j][k] * Ww[k]
//   t[j]        = sum_k x[j][k] * Ww[128+k]
// One block per row j, 128 threads (thread d owns output feature d).
// ---------------------------------------------------------------------------
__global__ __launch_bounds__(128) void proj_kernel(
    const float* __restrict__ x,
    const float* __restrict__ Wf,
    const float* __restrict__ Ww,
    float* __restrict__ fsrc,
    float* __restrict__ ftgt,
    float* __restrict__ s,
    float* __restrict__ t)
{
    const int j = blockIdx.x;
    const int d = threadIdx.x;  // 0..127

    __shared__ float xj[DI];
    xj[d] = x[j * DI + d];
    __syncthreads();

    // dense projections: thread d does two dot-128s against Wf row d
    const float* wrow = Wf + d * (2 * DI);
    float a0 = 0.f, a1 = 0.f;
#pragma unroll 8
    for (int k = 0; k < DI; ++k) {
        const float xv = xj[k];
        a0 += xv * wrow[k];
        a1 += xv * wrow[DI + k];
    }
    fsrc[j * DO + d] = a0;
    ftgt[j * DO + d] = a1;

    // attention scalars: block-wide reduction of x[j]*w_src and x[j]*w_tgt
    float vs = xj[d] * Ww[d];
    float vt = xj[d] * Ww[DI + d];
    for (int off = 32; off >= 1; off >>= 1) {
        vs += __shfl_down(vs, off);
        vt += __shfl_down(vt, off);
    }
    __shared__ float rs[2], rt[2];
    const int wid = d >> 6;
    if ((d & 63) == 0) { rs[wid] = vs; rt[wid] = vt; }
    __syncthreads();
    if (d == 0) {
        s[j] = rs[0] + rs[1];
        t[j] = rt[0] + rt[1];
    }
}

// ---------------------------------------------------------------------------
// Kernel B: one block per output row i, 256 threads.
//   1) masked scores  a[i,j] = s[j] + t[i] + bw   (adj==0 -> -1e16)
//   2) row softmax -> p[512] in LDS, also written out as a_att
//   3) o[i,d] = sum_j p[j] * relu(f_src[j,d] + f_tgt[i,d] + bf[d])
//      (2 threads per d, each covers 256 j's, combined via LDS)
// ---------------------------------------------------------------------------
__global__ __launch_bounds__(256) void gat_row_kernel(
    const int*   __restrict__ adj,
    const float* __restrict__ fsrc,
    const float* __restrict__ ftgt,
    const float* __restrict__ s,
    const float* __restrict__ t,
    const float* __restrict__ bf,
    const float* __restrict__ bw,
    float* __restrict__ out)   // [0 .. N*DO) = o, [N*DO .. N*DO + N*N) = a_att
{
    const int i   = blockIdx.x;
    const int tid = threadIdx.x;  // 0..255

    __shared__ float p[N];
    __shared__ float redmax[4];
    __shared__ float redsum[4];
    __shared__ float oacc[DO];

    const float t_i = t[i] + bw[0];

    // ---- phase 1: masked scores (2 j's per thread) ----
    const int j0 = tid, j1 = tid + 256;
    const float a0 = s[j0] + t_i;
    const float a1 = s[j1] + t_i;
    const float v0 = (adj[i * N + j0] > 0) ? a0 : -1e16f;
    const float v1 = (adj[i * N + j1] > 0) ? a1 : -1e16f;

    // ---- row max ----
    float m = fmaxf(v0, v1);
    for (int off = 32; off >= 1; off >>= 1)
        m = fmaxf(m, __shfl_down(m, off));
    if ((tid & 63) == 0) redmax[tid >> 6] = m;
    __syncthreads();
    m = fmaxf(fmaxf(redmax[0], redmax[1]), fmaxf(redmax[2], redmax[3]));

    // ---- exp + row sum ----
    const float e0 = __expf(v0 - m);
    const float e1 = __expf(v1 - m);
    float sum = e0 + e1;
    for (int off = 32; off >= 1; off >>= 1)
        sum += __shfl_down(sum, off);
    if ((tid & 63) == 0) redsum[tid >> 6] = sum;
    __syncthreads();
    sum = redsum[0] + redsum[1] + redsum[2] + redsum[3];
    const float inv = 1.0f / sum;

    const float p0 = e0 * inv;
    const float p1 = e1 * inv;
    p[j0] = p0;
    p[j1] = p1;
    out[N * DO + i * N + j0] = p0;   // a_att row
    out[N * DO + i * N + j1] = p1;
    __syncthreads();

    // ---- phase 3: weighted ReLU contraction ----
    const int d     = tid & (DO - 1);
    const int jbase = (tid >> 7) * 256;
    const float ftb = ftgt[i * DO + d] + bf[d];

    float acc = 0.f;
#pragma unroll 4
    for (int j = jbase; j < jbase + 256; ++j) {
        const float w  = p[j];
        const float yv = fsrc[j * DO + d] + ftb;
        acc += w * fmaxf(yv, 0.f);
    }

    if (tid >= 128) oacc[d] = acc;
    __syncthreads();
    if (tid < 128) out[i * DO + d] = acc + oacc[d];
}

// ---------------------------------------------------------------------------
extern "C" void kernel_launch(void* const* d_in, const int* in_sizes, int n_in,
                              void* d_out, int out_size, void* d_ws, size_t ws_size,
                              hipStream_t stream) {
    const float* x   = (const float*)d_in[0];  // [512,128]
    const int*   adj = (const int*)  d_in[1];  // [512,512]
    const float* Wf  = (const float*)d_in[2];  // [128,256]
    const float* bf  = (const float*)d_in[3];  // [128]
    const float* Ww  = (const float*)d_in[4];  // [1,256]
    const float* bw  = (const float*)d_in[5];  // [1]
    float* out = (float*)d_out;

    // workspace layout (floats): fsrc[512*128] | ftgt[512*128] | s[512] | t[512]
    float* fsrc = (float*)d_ws;
    float* ftgt = fsrc + N * DO;
    float* s    = ftgt + N * DO;
    float* t    = s + N;

    proj_kernel<<<dim3(N), dim3(128), 0, stream>>>(x, Wf, Ww, fsrc, ftgt, s, t);
    gat_row_kernel<<<dim3(N), dim3(256), 0, stream>>>(adj, fsrc, ftgt, s, t, bf, bw, out);
}

// Round 2
// 21.562 us; speedup vs baseline: 1.6781x; 1.6781x over previous
//
#include <hip/hip_runtime.h>
#include <math.h>

#define N   512
#define DI  128
#define DO  128

// ---------------------------------------------------------------------------
// d_ws layout (floats):
//   WT  [128][256]   transposed weights: WT[k][c] = (c<128 ? Wf[c][k] : Wf[c-128][128+k])
//   fsrc[512][128]
//   ftgt[512][128]
//   s   [512]
//   t   [512]
// ---------------------------------------------------------------------------

// Transpose Wf into WT. Coalesced writes; reads are uncoalesced but total
// volume is only 128 KB (one wave-instr per block).
__global__ __launch_bounds__(256) void wt_kernel(
    const float* __restrict__ Wf, float* __restrict__ WT)
{
    const int k = blockIdx.x;    // 0..127
    const int c = threadIdx.x;   // 0..255
    WT[k * 256 + c] = Wf[(c & 127) * 256 + (c >> 7) * 128 + k];
}

// ---------------------------------------------------------------------------
// Projections: 2 rows per block, 256 threads, thread owns output column c.
//   c <  128: fsrc[j][c]   = sum_k x[j][k] * WT[k][c]
//   c >= 128: ftgt[j][c-128]
// x reads are wave-uniform (scalar loads); WT reads are coalesced.
// Also computes s[j], t[j] via per-wave shuffle reductions (waves 0,1 -> row 0
// s/t; waves 2,3 -> row 1 s/t).
// ---------------------------------------------------------------------------
__global__ __launch_bounds__(256) void proj_kernel(
    const float* __restrict__ x,
    const float* __restrict__ WT,
    const float* __restrict__ Ww,
    float* __restrict__ fsrc,
    float* __restrict__ ftgt,
    float* __restrict__ s,
    float* __restrict__ t)
{
    const int jb = blockIdx.x * 2;
    const int c  = threadIdx.x;   // 0..255

    const float* __restrict__ x0 = x + jb * DI;
    const float* __restrict__ x1 = x0 + DI;

    float acc0 = 0.f, acc1 = 0.f;
#pragma unroll 16
    for (int k = 0; k < DI; ++k) {
        const float wv = WT[k * 256 + c];
        acc0 += x0[k] * wv;   // x0[k], x1[k] are wave-uniform -> scalar loads
        acc1 += x1[k] * wv;
    }
    if (c < DO) {
        fsrc[(jb + 0) * DO + c] = acc0;
        fsrc[(jb + 1) * DO + c] = acc1;
    } else {
        ftgt[(jb + 0) * DO + (c - DO)] = acc0;
        ftgt[(jb + 1) * DO + (c - DO)] = acc1;
    }

    // s, t: wave w handles (row = w>>1, which = w&1 -> s or t)
    const int w = c >> 6;        // 0..3
    const int l = c & 63;
    const int row = jb + (w >> 1);
    const int half = (w & 1) * DI;   // 0 -> s (w_src), 128 -> t (w_tgt)
    const float* __restrict__ xr = x + row * DI;
    float v = xr[l] * Ww[half + l] + xr[64 + l] * Ww[half + 64 + l];
    for (int off = 32; off >= 1; off >>= 1)
        v += __shfl_down(v, off);
    if (l == 0) {
        if ((w & 1) == 0) s[row] = v;
        else              t[row] = v;
    }
}

// ---------------------------------------------------------------------------
// GAT main: 2 output rows (i0, i0+1) per block, 512 threads (8 waves).
// Phase 1: masked scores + softmax for both rows -> p[j][2] in LDS + a_att out.
// Phase 2: o[i][d] = sum_j p[j][i] * relu(fsrc[j][d] + ftgt[i][d] + bf[d]),
//          16 j-groups x 32 d-float4-groups, LDS tree reduction over groups.
// ---------------------------------------------------------------------------
__global__ __launch_bounds__(512) void gat_kernel(
    const int*   __restrict__ adj,
    const float* __restrict__ fsrc,
    const float* __restrict__ ftgt,
    const float* __restrict__ s,
    const float* __restrict__ t,
    const float* __restrict__ bf,
    const float* __restrict__ bw,
    float* __restrict__ out)   // [0..N*DO) = o, [N*DO..) = a_att
{
    const int i0  = blockIdx.x * 2;
    const int tid = threadIdx.x;  // 0..511

    __shared__ float p[N][2];          // 4 KB, p[j][r]
    __shared__ float red[16][2][DO];   // 16 KB
    __shared__ float rmax[2][4];
    __shared__ float rsum[2][4];

    // ---- phase 1: softmax rows i0 / i0+1 ----
    const int r  = tid >> 8;      // 0/1: which row
    const int jj = tid & 255;     // handles j = jj and jj+256
    const int i  = i0 + r;
    const float t_i = t[i] + bw[0];

    const float sc0 = s[jj] + t_i;
    const float sc1 = s[jj + 256] + t_i;
    const float v0 = (adj[i * N + jj] > 0)       ? sc0 : -1e16f;
    const float v1 = (adj[i * N + jj + 256] > 0) ? sc1 : -1e16f;

    const int wr = (tid >> 6) & 3;  // wave index within the row's 4 waves
    float m = fmaxf(v0, v1);
    for (int off = 32; off >= 1; off >>= 1)
        m = fmaxf(m, __shfl_down(m, off));
    if ((tid & 63) == 0) rmax[r][wr] = m;
    __syncthreads();
    m = fmaxf(fmaxf(rmax[r][0], rmax[r][1]), fmaxf(rmax[r][2], rmax[r][3]));

    const float e0 = __expf(v0 - m);
    const float e1 = __expf(v1 - m);
    float sum = e0 + e1;
    for (int off = 32; off >= 1; off >>= 1)
        sum += __shfl_down(sum, off);
    if ((tid & 63) == 0) rsum[r][wr] = sum;
    __syncthreads();
    sum = rsum[r][0] + rsum[r][1] + rsum[r][2] + rsum[r][3];
    const float inv = 1.0f / sum;

    const float p0 = e0 * inv;
    const float p1 = e1 * inv;
    p[jj][r]       = p0;
    p[jj + 256][r] = p1;
    out[N * DO + i * N + jj]       = p0;
    out[N * DO + i * N + jj + 256] = p1;
    __syncthreads();

    // ---- phase 2: weighted ReLU contraction ----
    const int c4 = (tid & 31) * 4;   // d base (float4)
    const int jg = tid >> 5;         // 0..15 j-group

    const float4 fA = *(const float4*)&ftgt[i0 * DO + c4];
    const float4 fB = *(const float4*)&ftgt[(i0 + 1) * DO + c4];
    const float4 bb = *(const float4*)&bf[c4];
    const float ftbAx = fA.x + bb.x, ftbAy = fA.y + bb.y,
                ftbAz = fA.z + bb.z, ftbAw = fA.w + bb.w;
    const float ftbBx = fB.x + bb.x, ftbBy = fB.y + bb.y,
                ftbBz = fB.z + bb.z, ftbBw = fB.w + bb.w;

    float ax = 0.f, ay = 0.f, az = 0.f, aw = 0.f;
    float bx = 0.f, by = 0.f, bz = 0.f, bw_ = 0.f;

    const int jstart = jg * 32;
#pragma unroll 8
    for (int j = jstart; j < jstart + 32; ++j) {
        const float4 f = *(const float4*)&fsrc[j * DO + c4];
        const float2 pv = *(const float2*)&p[j][0];
        const float yx = fmaxf(f.x + ftbAx, 0.f);
        const float yy = fmaxf(f.y + ftbAy, 0.f);
        const float yz = fmaxf(f.z + ftbAz, 0.f);
        const float yw = fmaxf(f.w + ftbAw, 0.f);
        ax += pv.x * yx; ay += pv.x * yy; az += pv.x * yz; aw += pv.x * yw;
        const float zx = fmaxf(f.x + ftbBx, 0.f);
        const float zy = fmaxf(f.y + ftbBy, 0.f);
        const float zz = fmaxf(f.z + ftbBz, 0.f);
        const float zw = fmaxf(f.w + ftbBw, 0.f);
        bx += pv.y * zx; by += pv.y * zy; bz += pv.y * zz; bw_ += pv.y * zw;
    }

    *(float4*)&red[jg][0][c4] = make_float4(ax, ay, az, aw);
    *(float4*)&red[jg][1][c4] = make_float4(bx, by, bz, bw_);
    __syncthreads();

    if (tid < 256) {
        const int rr = tid >> 7;     // row 0/1
        const int cc = tid & 127;    // feature
        float acc = 0.f;
#pragma unroll
        for (int g = 0; g < 16; ++g)
            acc += red[g][rr][cc];
        out[(i0 + rr) * DO + cc] = acc;
    }
}

// ---------------------------------------------------------------------------
extern "C" void kernel_launch(void* const* d_in, const int* in_sizes, int n_in,
                              void* d_out, int out_size, void* d_ws, size_t ws_size,
                              hipStream_t stream) {
    const float* x   = (const float*)d_in[0];  // [512,128]
    const int*   adj = (const int*)  d_in[1];  // [512,512]
    const float* Wf  = (const float*)d_in[2];  // [128,256]
    const float* bf  = (const float*)d_in[3];  // [128]
    const float* Ww  = (const float*)d_in[4];  // [1,256]
    const float* bw  = (const float*)d_in[5];  // [1]
    float* out = (float*)d_out;

    float* WT   = (float*)d_ws;           // 128*256
    float* fsrc = WT + 128 * 256;         // 512*128
    float* ftgt = fsrc + N * DO;          // 512*128
    float* s    = ftgt + N * DO;          // 512
    float* t    = s + N;                  // 512

    wt_kernel  <<<dim3(128), dim3(256), 0, stream>>>(Wf, WT);
    proj_kernel<<<dim3(256), dim3(256), 0, stream>>>(x, WT, Ww, fsrc, ftgt, s, t);
    gat_kernel <<<dim3(256), dim3(512), 0, stream>>>(adj, fsrc, ftgt, s, t, bf, bw, out);
}